// Round 6
// baseline (565.367 us; speedup 1.0000x reference)
//
#include <hip/hip_runtime.h>

typedef __attribute__((ext_vector_type(8))) short short8;
typedef __attribute__((ext_vector_type(4))) float f32x4;

#define NNODES 55296
#define DOUT 256

__device__ __forceinline__ float bf2f(unsigned short h) {
    union { unsigned u; float f; } x; x.u = ((unsigned)h) << 16; return x.f;
}
__device__ __forceinline__ unsigned short f2bf(float f) {
    union { float f; unsigned u; } x; x.f = f;
    return (unsigned short)((x.u + 0x7fffu + ((x.u >> 16) & 1u)) >> 16);
}

__device__ __forceinline__ void storev(float* p, float v) { *p = v; }
__device__ __forceinline__ void storev(unsigned short* p, float v) { *p = f2bf(v); }

// ---- fragment helpers ----
__device__ __forceinline__ short8 frag_self(const float* p) {
    float4 a = *(const float4*)p, b = *(const float4*)(p + 4);
    union { short8 s; unsigned short u[8]; } r;
    r.u[0] = f2bf(a.x); r.u[1] = f2bf(a.y); r.u[2] = f2bf(a.z); r.u[3] = f2bf(a.w);
    r.u[4] = f2bf(b.x); r.u[5] = f2bf(b.y); r.u[6] = f2bf(b.z); r.u[7] = f2bf(b.w);
    return r.s;
}
__device__ __forceinline__ short8 frag_self(const unsigned short* p) {
    return *(const short8*)p;
}
__device__ __forceinline__ void acc8(const float* p, float* o) {
    float4 a = *(const float4*)p, b = *(const float4*)(p + 4);
    o[0] += a.x; o[1] += a.y; o[2] += a.z; o[3] += a.w;
    o[4] += b.x; o[5] += b.y; o[6] += b.z; o[7] += b.w;
}
__device__ __forceinline__ void acc8(const unsigned short* p, float* o) {
    uint4 v = *(const uint4*)p;
    const unsigned short* u = (const unsigned short*)&v;
#pragma unroll
    for (int i = 0; i < 8; ++i) o[i] += bf2f(u[i]);
}
template <typename TIN>
__device__ __forceinline__ short8 frag_mean4(const TIN* p0, const TIN* p1,
                                             const TIN* p2, const TIN* p3) {
    float s[8] = {0.f, 0.f, 0.f, 0.f, 0.f, 0.f, 0.f, 0.f};
    acc8(p0, s); acc8(p1, s); acc8(p2, s); acc8(p3, s);
    union { short8 s8; unsigned short u[8]; } r;
#pragma unroll
    for (int i = 0; i < 8; ++i) r.u[i] = f2bf(s[i] * 0.25f);
    return r.s8;
}

// Wt[d][k] = bf16( k < C ? W_self[k][d] : W_neigh[k-C][d] )
__global__ void build_wt(const float* __restrict__ Ws,
                         const float* __restrict__ Wn,
                         unsigned short* __restrict__ Wt, int C) {
    int K2 = 2 * C;
    int idx = blockIdx.x * 256 + threadIdx.x;
    if (idx >= 256 * K2) return;
    int d = idx / K2;
    int k = idx - d * K2;
    float v = (k < C) ? Ws[(size_t)k * DOUT + d] : Wn[(size_t)(k - C) * DOUT + d];
    Wt[idx] = f2bf(v);
}

// ---- precompute hm[node][c] = bf16(mean of 4 neighbors) ----
template <int C, typename TIN>
__global__ __launch_bounds__(256) void mean_pass(const TIN* __restrict__ hin,
                                                 const int* __restrict__ nbr,
                                                 unsigned short* __restrict__ hm) {
    constexpr int CPL = C / 8;
    const int idx = blockIdx.x * 256 + threadIdx.x;
    const int node = idx / CPL;
    const int ch = (idx - node * CPL) * 8;
    const int b = node / NNODES;
    const int n = node - b * NNODES;
    const size_t bbase = (size_t)b * NNODES;
    const int4 nb = *(const int4*)(nbr + (size_t)n * 4);
    float s[8] = {0.f, 0.f, 0.f, 0.f, 0.f, 0.f, 0.f, 0.f};
    acc8(hin + (bbase + nb.x) * (size_t)C + ch, s);
    acc8(hin + (bbase + nb.y) * (size_t)C + ch, s);
    acc8(hin + (bbase + nb.z) * (size_t)C + ch, s);
    acc8(hin + (bbase + nb.w) * (size_t)C + ch, s);
    union { uint4 v; unsigned short u[8]; } r;
#pragma unroll
    for (int i = 0; i < 8; ++i) r.u[i] = f2bf(s[i] * 0.25f);
    *(uint4*)(hm + (size_t)node * C + ch) = r.v;
}

// ---- v6: B-tile K-staged through 64KB static LDS (2 blocks/CU -> 4 waves/SIMD).
// Stage 0: K=[0,C) (self, from hin); stage 1: K=[C,2C) (mean, from hm).
// A streamed global->reg, depth-2 buffer; acc carried across stages.
template <int C, typename TIN, typename TOUT>
__global__ __launch_bounds__(512, 4) void sage_v6(
    const TIN* __restrict__ hin,              // [M][C]
    const unsigned short* __restrict__ hm,    // [M][C] bf16
    const unsigned short* __restrict__ Wt,    // [256][2C] bf16, d-major
    const float* __restrict__ bias,           // [256]
    TOUT* __restrict__ out) {                 // [M][256]
    constexpr int K2 = 2 * C;
    constexpr int ROWB = C * 2;               // LDS bytes per row of stage tile (256/512)
    constexpr int LCOLS = 65536 / ROWB;       // 256 (L1) / 128 (L2)
    constexpr int CG = LCOLS / 64;            // wave col-groups: 4 / 2
    constexpr int RG = 8 / CG;                // wave row-groups: 2 / 4
    constexpr int CGRID = 256 / LCOLS;        // grid col splits: 1 / 2
    constexpr int NK = C / 32;                // phases per stage: 4 / 8
    __shared__ __align__(16) char Bs[65536];

    const int tid = threadIdx.x;
    const int bid = blockIdx.x;
    const int yg = bid % CGRID;               // col-split (pairs adjacent in grid)
    const int rb = bid / CGRID;
    const int gcol0 = yg * LCOLS;

    const int l = tid & 63;
    const int w = tid >> 6;
    const int rowg = w / CG;
    const int colb = (w % CG) * 64;
    const int lr = l & 15, lg = l >> 4;

    const int rowbase = rb * (RG * 64) + rowg * 64;
    const char* hb = (const char*)hin;
    const char* hmb = (const char*)hm;

    unsigned sofs[4], mofs[4];
#pragma unroll
    for (int m = 0; m < 4; ++m) {
        const int r = rowbase + m * 16 + lr;
        sofs[m] = (unsigned)(((size_t)r * C + lg * 8) * sizeof(TIN));
        mofs[m] = (unsigned)(((size_t)r * C + lg * 8) * 2);
    }

    f32x4 acc[4][4];
#pragma unroll
    for (int m = 0; m < 4; ++m)
#pragma unroll
        for (int j = 0; j < 4; ++j) acc[m][j] = (f32x4){0.f, 0.f, 0.f, 0.f};

    auto loadA0 = [&](int kk, short8* a) {
        const unsigned kb = (unsigned)(kk * 32) * sizeof(TIN);
#pragma unroll
        for (int m = 0; m < 4; ++m)
            a[m] = frag_self((const TIN*)(hb + sofs[m] + kb));
    };
    auto loadA1 = [&](int kk, short8* a) {
        const unsigned kb = (unsigned)(kk * 32) * 2;
#pragma unroll
        for (int m = 0; m < 4; ++m)
            a[m] = *(const short8*)(hmb + mofs[m] + kb);
    };
    auto stageB = [&](int s) {
        const unsigned short* wsrc = Wt + (size_t)gcol0 * K2 + (size_t)s * C;
#pragma unroll
        for (int i = 0; i < 8; ++i) {
            int byt = (i * 512 + tid) * 16;
            int c = byt / ROWB;          // local col
            int kloc2 = byt - c * ROWB;  // byte offset within row
            uint4 v = *(const uint4*)((const char*)(wsrc + (size_t)c * K2) + kloc2);
            *(uint4*)(Bs + (byt ^ ((c & 7) << 4))) = v;
        }
    };

    short8 ab[2][4];

    // ================ stage 0: self half ================
    loadA0(0, ab[0]);
    loadA0(1, ab[1]);
    stageB(0);
    __syncthreads();
#pragma unroll
    for (int kk = 0; kk < NK; ++kk) {
        short8 cur[4];
#pragma unroll
        for (int m = 0; m < 4; ++m) cur[m] = ab[kk & 1][m];
        if (kk + 2 < NK) loadA0(kk + 2, ab[kk & 1]);
#pragma unroll
        for (int j = 0; j < 4; ++j) {
            const int cl = colb + j * 16 + lr;
            const short8 bf = *(const short8*)(
                Bs + ((cl * ROWB + (kk * 32 + lg * 8) * 2) ^ ((l & 7) << 4)));
#pragma unroll
            for (int m = 0; m < 4; ++m)
                acc[m][j] = __builtin_amdgcn_mfma_f32_16x16x32_bf16(cur[m], bf, acc[m][j], 0, 0, 0);
        }
    }
    __syncthreads();

    // ================ stage 1: mean half ================
    loadA1(0, ab[0]);
    loadA1(1, ab[1]);
    stageB(1);
    __syncthreads();
#pragma unroll
    for (int kk = 0; kk < NK; ++kk) {
        short8 cur[4];
#pragma unroll
        for (int m = 0; m < 4; ++m) cur[m] = ab[kk & 1][m];
        if (kk + 2 < NK) loadA1(kk + 2, ab[kk & 1]);
#pragma unroll
        for (int j = 0; j < 4; ++j) {
            const int cl = colb + j * 16 + lr;
            const short8 bf = *(const short8*)(
                Bs + ((cl * ROWB + (kk * 32 + lg * 8) * 2) ^ ((l & 7) << 4)));
#pragma unroll
            for (int m = 0; m < 4; ++m)
                acc[m][j] = __builtin_amdgcn_mfma_f32_16x16x32_bf16(cur[m], bf, acc[m][j], 0, 0, 0);
        }
    }

    // ---- epilogue: bias + relu + store ----
#pragma unroll
    for (int j = 0; j < 4; ++j) {
        const int gcol = gcol0 + colb + j * 16 + lr;
        const float bv = bias[gcol];
#pragma unroll
        for (int m = 0; m < 4; ++m) {
#pragma unroll
            for (int r = 0; r < 4; ++r) {
                const int row = rowbase + m * 16 + lg * 4 + r;
                storev(out + (size_t)row * DOUT + gcol, fmaxf(acc[m][j][r] + bv, 0.f));
            }
        }
    }
}

// ---- v3 (round-3 kernel), fallback when ws is too small for mean buffers ----
template <int C, typename TIN, typename TOUT>
__global__ __launch_bounds__(512, 2) void sage_v3(
    const TIN* __restrict__ hin, const int* __restrict__ nbr,
    const unsigned short* __restrict__ Wt, const float* __restrict__ bias,
    TOUT* __restrict__ out) {
    constexpr int K2 = 2 * C;
    constexpr int ROWB = K2 * 2;
    constexpr int LCOLS = 131072 / ROWB;
    constexpr int CG = LCOLS / 128;
    constexpr int RG = 8 / CG;
    extern __shared__ char Bs[];

    const int tid = threadIdx.x;
    const int gcol0 = blockIdx.y * LCOLS;
    {
        const char* src = (const char*)(Wt + (size_t)gcol0 * K2);
#pragma unroll
        for (int i = 0; i < 16; ++i) {
            int byt = (i * 512 + tid) * 16;
            uint4 v = *(const uint4*)(src + byt);
            int c = byt / ROWB;
            *(uint4*)(Bs + (byt ^ ((c & 7) << 4))) = v;
        }
    }
    __syncthreads();

    const int l = tid & 63;
    const int w = tid >> 6;
    const int rowg = w / CG;
    const int colb = (w % CG) * 128;
    const int lr = l & 15, lg = l >> 4;

    const int rowbase = blockIdx.x * (RG * 64) + rowg * 64;
    const int bb = rowbase / NNODES;
    const int n0 = rowbase - bb * NNODES;
    const size_t bbase = (size_t)bb * NNODES;

    unsigned soff[4], noff[4][4];
#pragma unroll
    for (int m = 0; m < 4; ++m) {
        int r = m * 16 + lr;
        soff[m] = (unsigned)(((rowbase + r) * (size_t)C + lg * 8) * sizeof(TIN));
        int4 nb = *(const int4*)(nbr + (size_t)(n0 + r) * 4);
        noff[m][0] = (unsigned)(((bbase + nb.x) * C + lg * 8) * sizeof(TIN));
        noff[m][1] = (unsigned)(((bbase + nb.y) * C + lg * 8) * sizeof(TIN));
        noff[m][2] = (unsigned)(((bbase + nb.z) * C + lg * 8) * sizeof(TIN));
        noff[m][3] = (unsigned)(((bbase + nb.w) * C + lg * 8) * sizeof(TIN));
    }
    const char* hb = (const char*)hin;

    f32x4 acc[4][8];
#pragma unroll
    for (int m = 0; m < 4; ++m)
#pragma unroll
        for (int j = 0; j < 8; ++j) acc[m][j] = (f32x4){0.f, 0.f, 0.f, 0.f};

#pragma unroll
    for (int kk = 0; kk < K2 / 32; ++kk) {
        const int k0 = kk * 32;
        short8 a[4];
        if (k0 < C) {
            const unsigned kb = k0 * sizeof(TIN);
#pragma unroll
            for (int m = 0; m < 4; ++m)
                a[m] = frag_self((const TIN*)(hb + soff[m] + kb));
        } else {
            const unsigned kb = (k0 - C) * sizeof(TIN);
#pragma unroll
            for (int m = 0; m < 4; ++m)
                a[m] = frag_mean4((const TIN*)(hb + noff[m][0] + kb),
                                  (const TIN*)(hb + noff[m][1] + kb),
                                  (const TIN*)(hb + noff[m][2] + kb),
                                  (const TIN*)(hb + noff[m][3] + kb));
        }
#pragma unroll
        for (int j = 0; j < 8; ++j) {
            const int c = colb + j * 16 + lr;
            const short8 bf = *(const short8*)(
                Bs + ((c * ROWB + (k0 + lg * 8) * 2) ^ ((l & 7) << 4)));
#pragma unroll
            for (int m = 0; m < 4; ++m)
                acc[m][j] = __builtin_amdgcn_mfma_f32_16x16x32_bf16(a[m], bf, acc[m][j], 0, 0, 0);
        }
    }

#pragma unroll
    for (int j = 0; j < 8; ++j) {
        const int gcol = gcol0 + colb + j * 16 + lr;
        const float bv = bias[gcol];
#pragma unroll
        for (int m = 0; m < 4; ++m) {
#pragma unroll
            for (int r = 0; r < 4; ++r) {
                const int row = rowbase + m * 16 + lg * 4 + r;
                storev(out + (size_t)row * DOUT + gcol, fmaxf(acc[m][j][r] + bv, 0.f));
            }
        }
    }
}

extern "C" void kernel_launch(void* const* d_in, const int* in_sizes, int n_in,
                              void* d_out, int out_size, void* d_ws, size_t ws_size,
                              hipStream_t stream) {
    const float* x = (const float*)d_in[0];
    const int* nbr = (const int*)d_in[1];
    const float* Ws1 = (const float*)d_in[2];
    const float* Wn1 = (const float*)d_in[3];
    const float* b1 = (const float*)d_in[4];
    const float* Ws2 = (const float*)d_in[5];
    const float* Wn2 = (const float*)d_in[6];
    const float* b2 = (const float*)d_in[7];
    float* out = (float*)d_out;

    const int B = in_sizes[0] / (NNODES * 128);  // 4
    const int M = B * NNODES;                    // 221184

    char* ws = (char*)d_ws;
    const size_t h1_bytes = (size_t)M * DOUT * 2;
    const size_t hm_bytes = (size_t)M * DOUT * 2;
    const size_t need = h1_bytes + hm_bytes + 131072 + 262144;

    if (ws_size >= need) {
        unsigned short* h1 = (unsigned short*)ws;
        unsigned short* hm = (unsigned short*)(ws + h1_bytes);
        unsigned short* Wt1 = (unsigned short*)(ws + h1_bytes + hm_bytes);
        unsigned short* Wt2 = Wt1 + 256 * 256;

        build_wt<<<256, 256, 0, stream>>>(Ws1, Wn1, Wt1, 128);
        build_wt<<<512, 256, 0, stream>>>(Ws2, Wn2, Wt2, 256);

        // layer 1: block = 128 rows x 256 cols (all cols; A read once)
        mean_pass<128, float><<<M * 16 / 256, 256, 0, stream>>>(x, nbr, hm);
        sage_v6<128, float, unsigned short>
            <<<M / 128, 512, 0, stream>>>(x, hm, Wt1, b1, h1);
        // layer 2: block = 256 rows x 128 cols, col-pairs adjacent in grid
        mean_pass<256, unsigned short><<<M * 32 / 256, 256, 0, stream>>>(h1, nbr, hm);
        sage_v6<256, unsigned short, float>
            <<<(M / 256) * 2, 512, 0, stream>>>(h1, hm, Wt2, b2, out);
    } else {
        unsigned short* h1 = (unsigned short*)ws;
        unsigned short* Wt1 = (unsigned short*)(ws + h1_bytes);
        unsigned short* Wt2 = Wt1 + 256 * 256;

        build_wt<<<256, 256, 0, stream>>>(Ws1, Wn1, Wt1, 128);
        build_wt<<<512, 256, 0, stream>>>(Ws2, Wn2, Wt2, 256);

        hipFuncSetAttribute((const void*)sage_v3<128, float, unsigned short>,
                            hipFuncAttributeMaxDynamicSharedMemorySize, 131072);
        hipFuncSetAttribute((const void*)sage_v3<256, unsigned short, float>,
                            hipFuncAttributeMaxDynamicSharedMemorySize, 131072);

        sage_v3<128, float, unsigned short>
            <<<dim3(M / 256, 1), 512, 131072, stream>>>(x, nbr, Wt1, b1, h1);
        sage_v3<256, unsigned short, float>
            <<<dim3(M / 512, 2), 512, 131072, stream>>>(h1, nbr, Wt2, b2, out);
    }
}

// Round 8
// 362.298 us; speedup vs baseline: 1.5605x; 1.5605x over previous
//
#include <hip/hip_runtime.h>
#include <stdint.h>

typedef __attribute__((ext_vector_type(8))) short short8;
typedef __attribute__((ext_vector_type(4))) float f32x4;

#define NNODES 55296
#define DOUT 256

#define WAIT_VM(N) asm volatile("s_waitcnt vmcnt(" #N ")" ::: "memory")
#define SOFT_FENCE asm volatile("" ::: "memory")

__device__ __forceinline__ float bf2f(unsigned short h) {
    union { unsigned u; float f; } x; x.u = ((unsigned)h) << 16; return x.f;
}
__device__ __forceinline__ unsigned short f2bf(float f) {
    union { float f; unsigned u; } x; x.f = f;
    return (unsigned short)((x.u + 0x7fffu + ((x.u >> 16) & 1u)) >> 16);
}

__device__ __forceinline__ void storev(float* p, float v) { *p = v; }
__device__ __forceinline__ void storev(unsigned short* p, float v) { *p = f2bf(v); }

__device__ __forceinline__ void dma16(const void* g, void* l) {
    __builtin_amdgcn_global_load_lds(
        reinterpret_cast<const unsigned int __attribute__((address_space(1)))*>((uintptr_t)g),
        reinterpret_cast<unsigned int __attribute__((address_space(3)))*>((uintptr_t)l),
        16, 0, 0);
}

// ---- fragment helpers ----
__device__ __forceinline__ short8 frag_self(const float* p) {
    float4 a = *(const float4*)p, b = *(const float4*)(p + 4);
    union { short8 s; unsigned short u[8]; } r;
    r.u[0] = f2bf(a.x); r.u[1] = f2bf(a.y); r.u[2] = f2bf(a.z); r.u[3] = f2bf(a.w);
    r.u[4] = f2bf(b.x); r.u[5] = f2bf(b.y); r.u[6] = f2bf(b.z); r.u[7] = f2bf(b.w);
    return r.s;
}
__device__ __forceinline__ short8 frag_self(const unsigned short* p) {
    return *(const short8*)p;
}
__device__ __forceinline__ void acc8(const float* p, float* o) {
    float4 a = *(const float4*)p, b = *(const float4*)(p + 4);
    o[0] += a.x; o[1] += a.y; o[2] += a.z; o[3] += a.w;
    o[4] += b.x; o[5] += b.y; o[6] += b.z; o[7] += b.w;
}
__device__ __forceinline__ void acc8(const unsigned short* p, float* o) {
    uint4 v = *(const uint4*)p;
    const unsigned short* u = (const unsigned short*)&v;
#pragma unroll
    for (int i = 0; i < 8; ++i) o[i] += bf2f(u[i]);
}
template <typename TIN>
__device__ __forceinline__ short8 frag_mean4(const TIN* p0, const TIN* p1,
                                             const TIN* p2, const TIN* p3) {
    float s[8] = {0.f, 0.f, 0.f, 0.f, 0.f, 0.f, 0.f, 0.f};
    acc8(p0, s); acc8(p1, s); acc8(p2, s); acc8(p3, s);
    union { short8 s8; unsigned short u[8]; } r;
#pragma unroll
    for (int i = 0; i < 8; ++i) r.u[i] = f2bf(s[i] * 0.25f);
    return r.s8;
}

// Wt[d][k] = bf16( k < C ? W_self[k][d] : W_neigh[k-C][d] )
__global__ void build_wt(const float* __restrict__ Ws,
                         const float* __restrict__ Wn,
                         unsigned short* __restrict__ Wt, int C) {
    int K2 = 2 * C;
    int idx = blockIdx.x * 256 + threadIdx.x;
    if (idx >= 256 * K2) return;
    int d = idx / K2;
    int k = idx - d * K2;
    float v = (k < C) ? Ws[(size_t)k * DOUT + d] : Wn[(size_t)(k - C) * DOUT + d];
    Wt[idx] = f2bf(v);
}

// ---- precompute hm[node][c] = bf16(mean of 4 neighbors) ----
template <int C, typename TIN>
__global__ __launch_bounds__(256) void mean_pass(const TIN* __restrict__ hin,
                                                 const int* __restrict__ nbr,
                                                 unsigned short* __restrict__ hm) {
    constexpr int CPL = C / 8;
    const int idx = blockIdx.x * 256 + threadIdx.x;
    const int node = idx / CPL;
    const int ch = (idx - node * CPL) * 8;
    const int b = node / NNODES;
    const int n = node - b * NNODES;
    const size_t bbase = (size_t)b * NNODES;
    const int4 nb = *(const int4*)(nbr + (size_t)n * 4);
    float s[8] = {0.f, 0.f, 0.f, 0.f, 0.f, 0.f, 0.f, 0.f};
    acc8(hin + (bbase + nb.x) * (size_t)C + ch, s);
    acc8(hin + (bbase + nb.y) * (size_t)C + ch, s);
    acc8(hin + (bbase + nb.z) * (size_t)C + ch, s);
    acc8(hin + (bbase + nb.w) * (size_t)C + ch, s);
    union { uint4 v; unsigned short u[8]; } r;
#pragma unroll
    for (int i = 0; i < 8; ++i) r.u[i] = f2bf(s[i] * 0.25f);
    *(uint4*)(hm + (size_t)node * C + ch) = r.v;
}

// ---- v7 (layer 2 only, C=256): DMA-pipelined A ring + K-staged weights ----
// LDS: [0,64K) W-tile: 128 cols x 512B (one K-half), XOR (col&7)<<4
//      [64K,128K) A ring: 4 bufs x 16KB, [256 rows][64B], slot ^= row&3
// Phases p=0..15: p<8 reads h1 (self K-half), p>=8 reads hm (mean K-half).
// Counted vmcnt(4) steady state; one raw barrier/phase; W restaged at p==8.
__global__ __launch_bounds__(512) void sage_v7_l2(
    const unsigned short* __restrict__ h1p,   // [M][256] bf16
    const unsigned short* __restrict__ hmp,   // [M][256] bf16
    const unsigned short* __restrict__ Wt,    // [256][512] bf16, d-major
    const float* __restrict__ bias,           // [256]
    float* __restrict__ out) {                // [M][256] f32
    extern __shared__ char lds[];
    const int tid = threadIdx.x;
    const int bid = blockIdx.x;
    const int yg = bid & 1;          // col half; pairs adjacent for L2/L3 reuse
    const int rb = bid >> 1;
    const int gcol0 = yg * 128;
    const int rowbase = rb * 256;

    const int l = tid & 63;
    const int w = tid >> 6;
    const int lr = l & 15, lg = l >> 4;
    const int rowg = w >> 1;         // 0..3 -> 64-row group
    const int colb = (w & 1) * 64;   // 0/64 local col group

    const char* wsrc = (const char*)Wt + (size_t)gcol0 * 1024;  // row stride 1024B

    auto stageW = [&](int s) {
#pragma unroll
        for (int i = 0; i < 8; ++i) {
            int o = (tid + i * 512) * 16;
            int col = o >> 9, kb = o & 511;
            uint4 v = *(const uint4*)(wsrc + (size_t)col * 1024 + s * 512 + kb);
            *(uint4*)(lds + (o ^ ((col & 7) << 4))) = v;
        }
    };

    auto issueA = [&](int p) {
        const char* base = (p < 8) ? (const char*)h1p : (const char*)hmp;
        const int kb = (p & 7) * 64;
        char* ldst = lds + 65536 + (p & 3) * 16384 + w * 1024;
#pragma unroll
        for (int i = 0; i < 2; ++i) {
            int c = tid + i * 512;
            int row = c >> 2, slot = c & 3;
            const char* src = base + (size_t)(rowbase + row) * 512 + kb +
                              ((slot ^ (row & 3)) << 4);
            dma16(src, ldst + i * 8192);
        }
    };

    // prologue: start A pipeline, stage W half 0
    issueA(0); issueA(1); issueA(2);
    stageW(0);
    __syncthreads();

    f32x4 acc[4][4];
#pragma unroll
    for (int m = 0; m < 4; ++m)
#pragma unroll
        for (int j = 0; j < 4; ++j) acc[m][j] = (f32x4){0.f, 0.f, 0.f, 0.f};

    int arow0[4];
#pragma unroll
    for (int m = 0; m < 4; ++m) arow0[m] = rowg * 64 + m * 16 + lr;

#pragma unroll
    for (int kk = 0; kk < 16; ++kk) {
        if (kk <= 13) { WAIT_VM(4); }
        else if (kk == 14) { WAIT_VM(2); }
        else { WAIT_VM(0); }
        __builtin_amdgcn_s_barrier();
        SOFT_FENCE;
        if (kk == 8) {            // swap in mean-half weights (once)
            stageW(1);
            __syncthreads();
        }
        if (kk + 3 < 16) issueA(kk + 3);

        const int bufo = 65536 + (kk & 3) * 16384;
        short8 af[4], wf[4];
#pragma unroll
        for (int m = 0; m < 4; ++m) {
            const int ar = arow0[m];
            af[m] = *(const short8*)(lds + bufo + ar * 64 + ((lg ^ (ar & 3)) << 4));
        }
#pragma unroll
        for (int j = 0; j < 4; ++j) {
            const int col = colb + j * 16 + lr;
            wf[j] = *(const short8*)(
                lds + (((col << 9) + ((kk & 7) << 6) + (lg << 4)) ^ ((lr & 7) << 4)));
        }
#pragma unroll
        for (int j = 0; j < 4; ++j)
#pragma unroll
            for (int m = 0; m < 4; ++m)
                acc[m][j] = __builtin_amdgcn_mfma_f32_16x16x32_bf16(af[m], wf[j], acc[m][j], 0, 0, 0);
        SOFT_FENCE;
    }

    // epilogue: bias + relu + f32 store  (row includes rowg*64 — round-7 bug fix)
#pragma unroll
    for (int j = 0; j < 4; ++j) {
        const int gcol = gcol0 + colb + j * 16 + lr;
        const float bv = bias[gcol];
#pragma unroll
        for (int m = 0; m < 4; ++m) {
#pragma unroll
            for (int r = 0; r < 4; ++r) {
                const int row = rowbase + rowg * 64 + m * 16 + lg * 4 + r;
                out[(size_t)row * DOUT + gcol] = fmaxf(acc[m][j][r] + bv, 0.f);
            }
        }
    }
}

// ---- v5 (round-5 kernel) for layer 1 ----
template <int C, typename TIN, typename TOUT>
__global__ __launch_bounds__(512, 2) void sage_v5(
    const TIN* __restrict__ hin, const unsigned short* __restrict__ hm,
    const unsigned short* __restrict__ Wt, const float* __restrict__ bias,
    TOUT* __restrict__ out) {
    constexpr int K2 = 2 * C;
    constexpr int ROWB = K2 * 2;
    constexpr int LCOLS = 131072 / ROWB;
    constexpr int CG = LCOLS / 64;
    constexpr int RG = 8 / CG;
    constexpr int CGRID = 256 / LCOLS;
    constexpr int NK = K2 / 32;
    constexpr int D = (sizeof(TIN) == 4) ? 3 : 4;
    extern __shared__ char Bs[];

    const int tid = threadIdx.x;
    const int bid = blockIdx.x;
    const int yg = bid % CGRID;
    const int rb = bid / CGRID;
    const int gcol0 = yg * LCOLS;

    {
        const char* src = (const char*)(Wt + (size_t)gcol0 * K2);
#pragma unroll
        for (int i = 0; i < 16; ++i) {
            int byt = (i * 512 + tid) * 16;
            uint4 v = *(const uint4*)(src + byt);
            int c = byt / ROWB;
            *(uint4*)(Bs + (byt ^ ((c & 7) << 4))) = v;
        }
    }
    __syncthreads();

    const int l = tid & 63;
    const int w = tid >> 6;
    const int rowg = w / CG;
    const int colb = (w % CG) * 64;
    const int lr = l & 15, lg = l >> 4;

    const int rowbase = rb * (RG * 64) + rowg * 64;
    const char* hb = (const char*)hin;
    const char* hmb = (const char*)hm;

    unsigned sofs[4], mofs[4];
#pragma unroll
    for (int m = 0; m < 4; ++m) {
        const int r = rowbase + m * 16 + lr;
        sofs[m] = (unsigned)(((size_t)r * C + lg * 8) * sizeof(TIN));
        mofs[m] = (unsigned)(((size_t)r * C + lg * 8) * 2);
    }

    f32x4 acc[4][4];
#pragma unroll
    for (int m = 0; m < 4; ++m)
#pragma unroll
        for (int j = 0; j < 4; ++j) acc[m][j] = (f32x4){0.f, 0.f, 0.f, 0.f};

    auto loadA = [&](int kk, short8* a) {
        const int k0 = kk * 32;
        if (k0 < C) {
#pragma unroll
            for (int m = 0; m < 4; ++m)
                a[m] = frag_self((const TIN*)(hb + sofs[m] + (unsigned)k0 * sizeof(TIN)));
        } else {
#pragma unroll
            for (int m = 0; m < 4; ++m)
                a[m] = *(const short8*)(hmb + mofs[m] + (unsigned)(k0 - C) * 2);
        }
    };

    short8 ab[D][4];
#pragma unroll
    for (int p = 0; p < D; ++p) loadA(p, ab[p]);

#pragma unroll
    for (int kk = 0; kk < NK; ++kk) {
        const int k0 = kk * 32;
        short8 cur[4];
#pragma unroll
        for (int m = 0; m < 4; ++m) cur[m] = ab[kk % D][m];
        if (kk + D < NK) loadA(kk + D, ab[kk % D]);
#pragma unroll
        for (int j = 0; j < 4; ++j) {
            const int c = colb + j * 16 + lr;
            const short8 bf = *(const short8*)(
                Bs + ((c * ROWB + (k0 + lg * 8) * 2) ^ ((l & 7) << 4)));
#pragma unroll
            for (int m = 0; m < 4; ++m)
                acc[m][j] = __builtin_amdgcn_mfma_f32_16x16x32_bf16(cur[m], bf, acc[m][j], 0, 0, 0);
        }
    }

#pragma unroll
    for (int j = 0; j < 4; ++j) {
        const int gcol = gcol0 + colb + j * 16 + lr;
        const float bv = bias[gcol];
#pragma unroll
        for (int m = 0; m < 4; ++m) {
#pragma unroll
            for (int r = 0; r < 4; ++r) {
                const int row = rowbase + m * 16 + lg * 4 + r;
                storev(out + (size_t)row * DOUT + gcol, fmaxf(acc[m][j][r] + bv, 0.f));
            }
        }
    }
}

// ---- v3 fallback (small ws): fused gather, weights all-K in LDS ----
template <int C, typename TIN, typename TOUT>
__global__ __launch_bounds__(512, 2) void sage_v3(
    const TIN* __restrict__ hin, const int* __restrict__ nbr,
    const unsigned short* __restrict__ Wt, const float* __restrict__ bias,
    TOUT* __restrict__ out) {
    constexpr int K2 = 2 * C;
    constexpr int ROWB = K2 * 2;
    constexpr int LCOLS = 131072 / ROWB;
    constexpr int CG = LCOLS / 128;
    constexpr int RG = 8 / CG;
    extern __shared__ char Bs[];

    const int tid = threadIdx.x;
    const int gcol0 = blockIdx.y * LCOLS;
    {
        const char* src = (const char*)(Wt + (size_t)gcol0 * K2);
#pragma unroll
        for (int i = 0; i < 16; ++i) {
            int byt = (i * 512 + tid) * 16;
            uint4 v = *(const uint4*)(src + byt);
            int c = byt / ROWB;
            *(uint4*)(Bs + (byt ^ ((c & 7) << 4))) = v;
        }
    }
    __syncthreads();

    const int l = tid & 63;
    const int w = tid >> 6;
    const int rowg = w / CG;
    const int colb = (w % CG) * 128;
    const int lr = l & 15, lg = l >> 4;

    const int rowbase = blockIdx.x * (RG * 64) + rowg * 64;
    const int bb = rowbase / NNODES;
    const int n0 = rowbase - bb * NNODES;
    const size_t bbase = (size_t)bb * NNODES;

    unsigned soff[4], noff[4][4];
#pragma unroll
    for (int m = 0; m < 4; ++m) {
        int r = m * 16 + lr;
        soff[m] = (unsigned)(((rowbase + r) * (size_t)C + lg * 8) * sizeof(TIN));
        int4 nb = *(const int4*)(nbr + (size_t)(n0 + r) * 4);
        noff[m][0] = (unsigned)(((bbase + nb.x) * C + lg * 8) * sizeof(TIN));
        noff[m][1] = (unsigned)(((bbase + nb.y) * C + lg * 8) * sizeof(TIN));
        noff[m][2] = (unsigned)(((bbase + nb.z) * C + lg * 8) * sizeof(TIN));
        noff[m][3] = (unsigned)(((bbase + nb.w) * C + lg * 8) * sizeof(TIN));
    }
    const char* hb = (const char*)hin;

    f32x4 acc[4][8];
#pragma unroll
    for (int m = 0; m < 4; ++m)
#pragma unroll
        for (int j = 0; j < 8; ++j) acc[m][j] = (f32x4){0.f, 0.f, 0.f, 0.f};

#pragma unroll
    for (int kk = 0; kk < K2 / 32; ++kk) {
        const int k0 = kk * 32;
        short8 a[4];
        if (k0 < C) {
            const unsigned kb = k0 * sizeof(TIN);
#pragma unroll
            for (int m = 0; m < 4; ++m)
                a[m] = frag_self((const TIN*)(hb + soff[m] + kb));
        } else {
            const unsigned kb = (k0 - C) * sizeof(TIN);
#pragma unroll
            for (int m = 0; m < 4; ++m)
                a[m] = frag_mean4((const TIN*)(hb + noff[m][0] + kb),
                                  (const TIN*)(hb + noff[m][1] + kb),
                                  (const TIN*)(hb + noff[m][2] + kb),
                                  (const TIN*)(hb + noff[m][3] + kb));
        }
#pragma unroll
        for (int j = 0; j < 8; ++j) {
            const int c = colb + j * 16 + lr;
            const short8 bf = *(const short8*)(
                Bs + ((c * ROWB + (k0 + lg * 8) * 2) ^ ((l & 7) << 4)));
#pragma unroll
            for (int m = 0; m < 4; ++m)
                acc[m][j] = __builtin_amdgcn_mfma_f32_16x16x32_bf16(a[m], bf, acc[m][j], 0, 0, 0);
        }
    }

#pragma unroll
    for (int j = 0; j < 8; ++j) {
        const int gcol = gcol0 + colb + j * 16 + lr;
        const float bv = bias[gcol];
#pragma unroll
        for (int m = 0; m < 4; ++m) {
#pragma unroll
            for (int r = 0; r < 4; ++r) {
                const int row = rowbase + m * 16 + lg * 4 + r;
                storev(out + (size_t)row * DOUT + gcol, fmaxf(acc[m][j][r] + bv, 0.f));
            }
        }
    }
}

extern "C" void kernel_launch(void* const* d_in, const int* in_sizes, int n_in,
                              void* d_out, int out_size, void* d_ws, size_t ws_size,
                              hipStream_t stream) {
    const float* x = (const float*)d_in[0];
    const int* nbr = (const int*)d_in[1];
    const float* Ws1 = (const float*)d_in[2];
    const float* Wn1 = (const float*)d_in[3];
    const float* b1 = (const float*)d_in[4];
    const float* Ws2 = (const float*)d_in[5];
    const float* Wn2 = (const float*)d_in[6];
    const float* b2 = (const float*)d_in[7];
    float* out = (float*)d_out;

    const int B = in_sizes[0] / (NNODES * 128);  // 4
    const int M = B * NNODES;                    // 221184

    char* ws = (char*)d_ws;
    const size_t h1_bytes = (size_t)M * DOUT * 2;
    const size_t hm_bytes = (size_t)M * DOUT * 2;
    const size_t need = h1_bytes + hm_bytes + 131072 + 262144;

    if (ws_size >= need) {
        unsigned short* h1 = (unsigned short*)ws;
        unsigned short* hm = (unsigned short*)(ws + h1_bytes);
        unsigned short* Wt1 = (unsigned short*)(ws + h1_bytes + hm_bytes);
        unsigned short* Wt2 = Wt1 + 256 * 256;

        build_wt<<<256, 256, 0, stream>>>(Ws1, Wn1, Wt1, 128);
        build_wt<<<512, 256, 0, stream>>>(Ws2, Wn2, Wt2, 256);

        hipFuncSetAttribute((const void*)sage_v5<128, float, unsigned short>,
                            hipFuncAttributeMaxDynamicSharedMemorySize, 131072);
        hipFuncSetAttribute((const void*)sage_v7_l2,
                            hipFuncAttributeMaxDynamicSharedMemorySize, 131072);

        // layer 1 (round-5 proven): block = 128 rows x 256 cols, A read once
        mean_pass<128, float><<<M * 16 / 256, 256, 0, stream>>>(x, nbr, hm);
        sage_v5<128, float, unsigned short>
            <<<M / 128, 512, 131072, stream>>>(x, hm, Wt1, b1, h1);
        // layer 2 (v7): DMA-pipelined; block = 256 rows x 128 cols, pairs adjacent
        mean_pass<256, unsigned short><<<M * 32 / 256, 256, 0, stream>>>(h1, nbr, hm);
        sage_v7_l2<<<(M / 256) * 2, 512, 131072, stream>>>(h1, hm, Wt2, b2, out);
    } else {
        unsigned short* h1 = (unsigned short*)ws;
        unsigned short* Wt1 = (unsigned short*)(ws + h1_bytes);
        unsigned short* Wt2 = Wt1 + 256 * 256;

        build_wt<<<256, 256, 0, stream>>>(Ws1, Wn1, Wt1, 128);
        build_wt<<<512, 256, 0, stream>>>(Ws2, Wn2, Wt2, 256);

        hipFuncSetAttribute((const void*)sage_v3<128, float, unsigned short>,
                            hipFuncAttributeMaxDynamicSharedMemorySize, 131072);
        hipFuncSetAttribute((const void*)sage_v3<256, unsigned short, float>,
                            hipFuncAttributeMaxDynamicSharedMemorySize, 131072);

        sage_v3<128, float, unsigned short>
            <<<dim3(M / 256, 1), 512, 131072, stream>>>(x, nbr, Wt1, b1, h1);
        sage_v3<256, unsigned short, float>
            <<<dim3(M / 512, 2), 512, 131072, stream>>>(h1, nbr, Wt2, b2, out);
    }
}

// Round 9
// 345.727 us; speedup vs baseline: 1.6353x; 1.0479x over previous
//
#include <hip/hip_runtime.h>
#include <stdint.h>

typedef __attribute__((ext_vector_type(8))) short short8;
typedef __attribute__((ext_vector_type(4))) float f32x4;

#define NNODES 55296
#define DOUT 256

#define WAIT_VM(N) asm volatile("s_waitcnt vmcnt(" #N ")" ::: "memory")
#define SOFT_FENCE asm volatile("" ::: "memory")

__device__ __forceinline__ float bf2f(unsigned short h) {
    union { unsigned u; float f; } x; x.u = ((unsigned)h) << 16; return x.f;
}
__device__ __forceinline__ unsigned short f2bf(float f) {
    union { float f; unsigned u; } x; x.f = f;
    return (unsigned short)((x.u + 0x7fffu + ((x.u >> 16) & 1u)) >> 16);
}

__device__ __forceinline__ void storev(float* p, float v) { *p = v; }
__device__ __forceinline__ void storev(unsigned short* p, float v) { *p = f2bf(v); }

__device__ __forceinline__ void dma16(const void* g, void* l) {
    __builtin_amdgcn_global_load_lds(
        reinterpret_cast<const unsigned int __attribute__((address_space(1)))*>((uintptr_t)g),
        reinterpret_cast<unsigned int __attribute__((address_space(3)))*>((uintptr_t)l),
        16, 0, 0);
}

// ---- fragment helpers (v3 fallback + mean kernels) ----
__device__ __forceinline__ short8 frag_self(const float* p) {
    float4 a = *(const float4*)p, b = *(const float4*)(p + 4);
    union { short8 s; unsigned short u[8]; } r;
    r.u[0] = f2bf(a.x); r.u[1] = f2bf(a.y); r.u[2] = f2bf(a.z); r.u[3] = f2bf(a.w);
    r.u[4] = f2bf(b.x); r.u[5] = f2bf(b.y); r.u[6] = f2bf(b.z); r.u[7] = f2bf(b.w);
    return r.s;
}
__device__ __forceinline__ short8 frag_self(const unsigned short* p) {
    return *(const short8*)p;
}
__device__ __forceinline__ void acc8(const float* p, float* o) {
    float4 a = *(const float4*)p, b = *(const float4*)(p + 4);
    o[0] += a.x; o[1] += a.y; o[2] += a.z; o[3] += a.w;
    o[4] += b.x; o[5] += b.y; o[6] += b.z; o[7] += b.w;
}
__device__ __forceinline__ void acc8(const unsigned short* p, float* o) {
    uint4 v = *(const uint4*)p;
    const unsigned short* u = (const unsigned short*)&v;
#pragma unroll
    for (int i = 0; i < 8; ++i) o[i] += bf2f(u[i]);
}
template <typename TIN>
__device__ __forceinline__ short8 frag_mean4(const TIN* p0, const TIN* p1,
                                             const TIN* p2, const TIN* p3) {
    float s[8] = {0.f, 0.f, 0.f, 0.f, 0.f, 0.f, 0.f, 0.f};
    acc8(p0, s); acc8(p1, s); acc8(p2, s); acc8(p3, s);
    union { short8 s8; unsigned short u[8]; } r;
#pragma unroll
    for (int i = 0; i < 8; ++i) r.u[i] = f2bf(s[i] * 0.25f);
    return r.s8;
}

// Wt[d][k] = bf16( k < C ? W_self[k][d] : W_neigh[k-C][d] )
__global__ void build_wt(const float* __restrict__ Ws,
                         const float* __restrict__ Wn,
                         unsigned short* __restrict__ Wt, int C) {
    int K2 = 2 * C;
    int idx = blockIdx.x * 256 + threadIdx.x;
    if (idx >= 256 * K2) return;
    int d = idx / K2;
    int k = idx - d * K2;
    float v = (k < C) ? Ws[(size_t)k * DOUT + d] : Wn[(size_t)(k - C) * DOUT + d];
    Wt[idx] = f2bf(v);
}

// ---- layer-1 prep: xm[node] = [ bf16(x[node]) (128) | mean4 neighbors (128) ] ----
__global__ __launch_bounds__(256) void mean_xb(const float* __restrict__ x,
                                               const int* __restrict__ nbr,
                                               unsigned short* __restrict__ xm) {
    const int idx = blockIdx.x * 256 + threadIdx.x;
    const int node = idx >> 4;
    const int ch = (idx & 15) * 8;
    const int b = node / NNODES;
    const int n = node - b * NNODES;
    const size_t bbase = (size_t)b * NNODES;
    const int4 nb = *(const int4*)(nbr + (size_t)n * 4);
    const float* ps = x + (size_t)node * 128 + ch;
    union { uint4 v; unsigned short u[8]; } rs, rm;
    float4 a0 = *(const float4*)ps, a1 = *(const float4*)(ps + 4);
    rs.u[0] = f2bf(a0.x); rs.u[1] = f2bf(a0.y); rs.u[2] = f2bf(a0.z); rs.u[3] = f2bf(a0.w);
    rs.u[4] = f2bf(a1.x); rs.u[5] = f2bf(a1.y); rs.u[6] = f2bf(a1.z); rs.u[7] = f2bf(a1.w);
    float s[8] = {0.f, 0.f, 0.f, 0.f, 0.f, 0.f, 0.f, 0.f};
    acc8(x + (bbase + nb.x) * 128 + ch, s);
    acc8(x + (bbase + nb.y) * 128 + ch, s);
    acc8(x + (bbase + nb.z) * 128 + ch, s);
    acc8(x + (bbase + nb.w) * 128 + ch, s);
#pragma unroll
    for (int i = 0; i < 8; ++i) rm.u[i] = f2bf(s[i] * 0.25f);
    *(uint4*)(xm + (size_t)node * 256 + ch) = rs.v;
    *(uint4*)(xm + (size_t)node * 256 + 128 + ch) = rm.v;
}

// ---- hm2[node][c] = bf16(mean of 4 neighbors of h1) ----
template <int C, typename TIN>
__global__ __launch_bounds__(256) void mean_pass(const TIN* __restrict__ hin,
                                                 const int* __restrict__ nbr,
                                                 unsigned short* __restrict__ hm) {
    constexpr int CPL = C / 8;
    const int idx = blockIdx.x * 256 + threadIdx.x;
    const int node = idx / CPL;
    const int ch = (idx - node * CPL) * 8;
    const int b = node / NNODES;
    const int n = node - b * NNODES;
    const size_t bbase = (size_t)b * NNODES;
    const int4 nb = *(const int4*)(nbr + (size_t)n * 4);
    float s[8] = {0.f, 0.f, 0.f, 0.f, 0.f, 0.f, 0.f, 0.f};
    acc8(hin + (bbase + nb.x) * (size_t)C + ch, s);
    acc8(hin + (bbase + nb.y) * (size_t)C + ch, s);
    acc8(hin + (bbase + nb.z) * (size_t)C + ch, s);
    acc8(hin + (bbase + nb.w) * (size_t)C + ch, s);
    union { uint4 v; unsigned short u[8]; } r;
#pragma unroll
    for (int i = 0; i < 8; ++i) r.u[i] = f2bf(s[i] * 0.25f);
    *(uint4*)(hm + (size_t)node * C + ch) = r.v;
}

// ---- v8 layer 1 (K2=256): DMA A-ring from single xm source; W-halves 64KB;
// block = 256 rows x 256 cols (A read once); 8 waves = 4 rowg x 2 colg(128).
// MFMA operands SWAPPED (wf, af): lane&15 = A-row, reg = W-col -> packed stores.
__global__ __launch_bounds__(512) void sage_v8_l1(
    const unsigned short* __restrict__ xm,    // [M][256] bf16 [self|mean]
    const unsigned short* __restrict__ Wt,    // [256 d][256 k] bf16
    const float* __restrict__ bias,           // [256]
    unsigned short* __restrict__ out) {       // [M][256] bf16
    extern __shared__ char lds[];
    const int tid = threadIdx.x;
    const int rowbase = blockIdx.x * 256;
    const int l = tid & 63, w = tid >> 6;
    const int lr = l & 15, lg = l >> 4;
    const int rowg = w >> 1;          // 4 row groups x 64 rows
    const int colb = (w & 1) * 128;   // 2 col groups x 128 cols
    const char* wsrc = (const char*)Wt;   // row stride 512B
    const char* xb = (const char*)xm;     // row stride 512B

    auto stageW = [&](int s) {        // 64KB: 256 cols x 256B (K-half s)
#pragma unroll
        for (int i = 0; i < 8; ++i) {
            int o = (tid + i * 512) * 16;
            int col = o >> 8, kb = o & 255;
            uint4 v = *(const uint4*)(wsrc + (size_t)col * 512 + s * 256 + kb);
            *(uint4*)(lds + (o ^ ((col & 7) << 4))) = v;
        }
    };
    auto issueA = [&](int p) {        // 16KB: 256 rows x 64B, slot ^ row&3
        const int kb = p * 64;
        char* ldst = lds + 65536 + (p & 3) * 16384 + w * 1024;
#pragma unroll
        for (int i = 0; i < 2; ++i) {
            int c = tid + i * 512;
            int row = c >> 2, slot = c & 3;
            const char* src = xb + (size_t)(rowbase + row) * 512 + kb +
                              ((slot ^ (row & 3)) << 4);
            dma16(src, ldst + i * 8192);
        }
    };

    issueA(0); issueA(1); issueA(2);
    stageW(0);
    __syncthreads();

    f32x4 acc[4][8];
#pragma unroll
    for (int m = 0; m < 4; ++m)
#pragma unroll
        for (int j = 0; j < 8; ++j) acc[m][j] = (f32x4){0.f, 0.f, 0.f, 0.f};

    int arow0[4];
#pragma unroll
    for (int m = 0; m < 4; ++m) arow0[m] = rowg * 64 + m * 16 + lr;

#pragma unroll
    for (int kk = 0; kk < 8; ++kk) {
        if (kk <= 5) { WAIT_VM(4); }
        else if (kk == 6) { WAIT_VM(2); }
        else { WAIT_VM(0); }
        __builtin_amdgcn_s_barrier();
        SOFT_FENCE;
        if (kk == 4) {            // swap in mean-half weights (once)
            stageW(1);
            __syncthreads();
        }
        if (kk + 3 < 8) issueA(kk + 3);

        const int bufo = 65536 + (kk & 3) * 16384;
        short8 af[4];
#pragma unroll
        for (int m = 0; m < 4; ++m) {
            const int ar = arow0[m];
            af[m] = *(const short8*)(lds + bufo + ar * 64 + ((lg ^ (ar & 3)) << 4));
        }
#pragma unroll
        for (int j = 0; j < 8; ++j) {
            const int col = colb + j * 16 + lr;
            const short8 wf = *(const short8*)(
                lds + ((col * 256 + (kk & 3) * 64 + lg * 16) ^ ((col & 7) << 4)));
#pragma unroll
            for (int m = 0; m < 4; ++m)
                acc[m][j] = __builtin_amdgcn_mfma_f32_16x16x32_bf16(wf, af[m], acc[m][j], 0, 0, 0);
        }
        SOFT_FENCE;
    }

    // epilogue (swapped layout): row = base+lr, 4 consecutive cols per lane
#pragma unroll
    for (int m = 0; m < 4; ++m) {
        const int row = rowbase + rowg * 64 + m * 16 + lr;
#pragma unroll
        for (int j = 0; j < 8; ++j) {
            const int c0 = colb + j * 16 + lg * 4;
            const float4 bv = *(const float4*)(bias + c0);
            union { unsigned short u[4]; uint2 v; } pk;
            pk.u[0] = f2bf(fmaxf(acc[m][j][0] + bv.x, 0.f));
            pk.u[1] = f2bf(fmaxf(acc[m][j][1] + bv.y, 0.f));
            pk.u[2] = f2bf(fmaxf(acc[m][j][2] + bv.z, 0.f));
            pk.u[3] = f2bf(fmaxf(acc[m][j][3] + bv.w, 0.f));
            *(uint2*)(out + (size_t)row * 256 + c0) = pk.v;
        }
    }
}

// ---- v8 layer 2 (K2=512): as round-8 v7_l2 but swapped MFMA + float4 stores ----
__global__ __launch_bounds__(512) void sage_v8_l2(
    const unsigned short* __restrict__ h1p,   // [M][256] bf16
    const unsigned short* __restrict__ hmp,   // [M][256] bf16
    const unsigned short* __restrict__ Wt,    // [256][512] bf16, d-major
    const float* __restrict__ bias,           // [256]
    float* __restrict__ out) {                // [M][256] f32
    extern __shared__ char lds[];
    const int tid = threadIdx.x;
    const int bid = blockIdx.x;
    const int yg = bid & 1;
    const int rb = bid >> 1;
    const int gcol0 = yg * 128;
    const int rowbase = rb * 256;

    const int l = tid & 63;
    const int w = tid >> 6;
    const int lr = l & 15, lg = l >> 4;
    const int rowg = w >> 1;
    const int colb = (w & 1) * 64;

    const char* wsrc = (const char*)Wt + (size_t)gcol0 * 1024;

    auto stageW = [&](int s) {
#pragma unroll
        for (int i = 0; i < 8; ++i) {
            int o = (tid + i * 512) * 16;
            int col = o >> 9, kb = o & 511;
            uint4 v = *(const uint4*)(wsrc + (size_t)col * 1024 + s * 512 + kb);
            *(uint4*)(lds + (o ^ ((col & 7) << 4))) = v;
        }
    };

    auto issueA = [&](int p) {
        const char* base = (p < 8) ? (const char*)h1p : (const char*)hmp;
        const int kb = (p & 7) * 64;
        char* ldst = lds + 65536 + (p & 3) * 16384 + w * 1024;
#pragma unroll
        for (int i = 0; i < 2; ++i) {
            int c = tid + i * 512;
            int row = c >> 2, slot = c & 3;
            const char* src = base + (size_t)(rowbase + row) * 512 + kb +
                              ((slot ^ (row & 3)) << 4);
            dma16(src, ldst + i * 8192);
        }
    };

    issueA(0); issueA(1); issueA(2);
    stageW(0);
    __syncthreads();

    f32x4 acc[4][4];
#pragma unroll
    for (int m = 0; m < 4; ++m)
#pragma unroll
        for (int j = 0; j < 4; ++j) acc[m][j] = (f32x4){0.f, 0.f, 0.f, 0.f};

    int arow0[4];
#pragma unroll
    for (int m = 0; m < 4; ++m) arow0[m] = rowg * 64 + m * 16 + lr;

#pragma unroll
    for (int kk = 0; kk < 16; ++kk) {
        if (kk <= 13) { WAIT_VM(4); }
        else if (kk == 14) { WAIT_VM(2); }
        else { WAIT_VM(0); }
        __builtin_amdgcn_s_barrier();
        SOFT_FENCE;
        if (kk == 8) {
            stageW(1);
            __syncthreads();
        }
        if (kk + 3 < 16) issueA(kk + 3);

        const int bufo = 65536 + (kk & 3) * 16384;
        short8 af[4], wf[4];
#pragma unroll
        for (int m = 0; m < 4; ++m) {
            const int ar = arow0[m];
            af[m] = *(const short8*)(lds + bufo + ar * 64 + ((lg ^ (ar & 3)) << 4));
        }
#pragma unroll
        for (int j = 0; j < 4; ++j) {
            const int col = colb + j * 16 + lr;
            wf[j] = *(const short8*)(
                lds + (((col << 9) + ((kk & 7) << 6) + (lg << 4)) ^ ((lr & 7) << 4)));
        }
#pragma unroll
        for (int j = 0; j < 4; ++j)
#pragma unroll
            for (int m = 0; m < 4; ++m)
                acc[m][j] = __builtin_amdgcn_mfma_f32_16x16x32_bf16(wf[j], af[m], acc[m][j], 0, 0, 0);
        SOFT_FENCE;
    }

    // epilogue (swapped layout): float4 stores, 4 consecutive cols per lane
#pragma unroll
    for (int m = 0; m < 4; ++m) {
        const int row = rowbase + rowg * 64 + m * 16 + lr;
#pragma unroll
        for (int j = 0; j < 4; ++j) {
            const int gcol = gcol0 + colb + j * 16 + lg * 4;
            const float4 bv = *(const float4*)(bias + gcol);
            float4 o;
            o.x = fmaxf(acc[m][j][0] + bv.x, 0.f);
            o.y = fmaxf(acc[m][j][1] + bv.y, 0.f);
            o.z = fmaxf(acc[m][j][2] + bv.z, 0.f);
            o.w = fmaxf(acc[m][j][3] + bv.w, 0.f);
            *(float4*)(out + (size_t)row * 256 + gcol) = o;
        }
    }
}

// ---- v3 fallback (small ws): fused gather, weights all-K in LDS ----
template <int C, typename TIN, typename TOUT>
__global__ __launch_bounds__(512, 2) void sage_v3(
    const TIN* __restrict__ hin, const int* __restrict__ nbr,
    const unsigned short* __restrict__ Wt, const float* __restrict__ bias,
    TOUT* __restrict__ out) {
    constexpr int K2 = 2 * C;
    constexpr int ROWB = K2 * 2;
    constexpr int LCOLS = 131072 / ROWB;
    constexpr int CG = LCOLS / 128;
    constexpr int RG = 8 / CG;
    extern __shared__ char Bs[];

    const int tid = threadIdx.x;
    const int gcol0 = blockIdx.y * LCOLS;
    {
        const char* src = (const char*)(Wt + (size_t)gcol0 * K2);
#pragma unroll
        for (int i = 0; i < 16; ++i) {
            int byt = (i * 512 + tid) * 16;
            uint4 v = *(const uint4*)(src + byt);
            int c = byt / ROWB;
            *(uint4*)(Bs + (byt ^ ((c & 7) << 4))) = v;
        }
    }
    __syncthreads();

    const int l = tid & 63;
    const int w = tid >> 6;
    const int rowg = w / CG;
    const int colb = (w % CG) * 128;
    const int lr = l & 15, lg = l >> 4;

    const int rowbase = blockIdx.x * (RG * 64) + rowg * 64;
    const int bb = rowbase / NNODES;
    const int n0 = rowbase - bb * NNODES;
    const size_t bbase = (size_t)bb * NNODES;

    unsigned soff[4], noff[4][4];
#pragma unroll
    for (int m = 0; m < 4; ++m) {
        int r = m * 16 + lr;
        soff[m] = (unsigned)(((rowbase + r) * (size_t)C + lg * 8) * sizeof(TIN));
        int4 nb = *(const int4*)(nbr + (size_t)(n0 + r) * 4);
        noff[m][0] = (unsigned)(((bbase + nb.x) * C + lg * 8) * sizeof(TIN));
        noff[m][1] = (unsigned)(((bbase + nb.y) * C + lg * 8) * sizeof(TIN));
        noff[m][2] = (unsigned)(((bbase + nb.z) * C + lg * 8) * sizeof(TIN));
        noff[m][3] = (unsigned)(((bbase + nb.w) * C + lg * 8) * sizeof(TIN));
    }
    const char* hb = (const char*)hin;

    f32x4 acc[4][8];
#pragma unroll
    for (int m = 0; m < 4; ++m)
#pragma unroll
        for (int j = 0; j < 8; ++j) acc[m][j] = (f32x4){0.f, 0.f, 0.f, 0.f};

#pragma unroll
    for (int kk = 0; kk < K2 / 32; ++kk) {
        const int k0 = kk * 32;
        short8 a[4];
        if (k0 < C) {
            const unsigned kb = k0 * sizeof(TIN);
#pragma unroll
            for (int m = 0; m < 4; ++m)
                a[m] = frag_self((const TIN*)(hb + soff[m] + kb));
        } else {
            const unsigned kb = (k0 - C) * sizeof(TIN);
#pragma unroll
            for (int m = 0; m < 4; ++m)
                a[m] = frag_mean4((const TIN*)(hb + noff[m][0] + kb),
                                  (const TIN*)(hb + noff[m][1] + kb),
                                  (const TIN*)(hb + noff[m][2] + kb),
                                  (const TIN*)(hb + noff[m][3] + kb));
        }
#pragma unroll
        for (int j = 0; j < 8; ++j) {
            const int c = colb + j * 16 + lr;
            const short8 bf = *(const short8*)(
                Bs + ((c * ROWB + (k0 + lg * 8) * 2) ^ ((l & 7) << 4)));
#pragma unroll
            for (int m = 0; m < 4; ++m)
                acc[m][j] = __builtin_amdgcn_mfma_f32_16x16x32_bf16(a[m], bf, acc[m][j], 0, 0, 0);
        }
    }

#pragma unroll
    for (int j = 0; j < 8; ++j) {
        const int gcol = gcol0 + colb + j * 16 + lr;
        const float bv = bias[gcol];
#pragma unroll
        for (int m = 0; m < 4; ++m) {
#pragma unroll
            for (int r = 0; r < 4; ++r) {
                const int row = rowbase + m * 16 + lg * 4 + r;
                storev(out + (size_t)row * DOUT + gcol, fmaxf(acc[m][j][r] + bv, 0.f));
            }
        }
    }
}

extern "C" void kernel_launch(void* const* d_in, const int* in_sizes, int n_in,
                              void* d_out, int out_size, void* d_ws, size_t ws_size,
                              hipStream_t stream) {
    const float* x = (const float*)d_in[0];
    const int* nbr = (const int*)d_in[1];
    const float* Ws1 = (const float*)d_in[2];
    const float* Wn1 = (const float*)d_in[3];
    const float* b1 = (const float*)d_in[4];
    const float* Ws2 = (const float*)d_in[5];
    const float* Wn2 = (const float*)d_in[6];
    const float* b2 = (const float*)d_in[7];
    float* out = (float*)d_out;

    const int B = in_sizes[0] / (NNODES * 128);  // 4
    const int M = B * NNODES;                    // 221184

    char* ws = (char*)d_ws;
    const size_t h1_bytes = (size_t)M * DOUT * 2;
    const size_t hm_bytes = (size_t)M * DOUT * 2;  // xm for L1, then hm2 for L2
    const size_t need = h1_bytes + hm_bytes + 131072 + 262144;

    if (ws_size >= need) {
        unsigned short* h1 = (unsigned short*)ws;
        unsigned short* xm = (unsigned short*)(ws + h1_bytes);  // reused as hm2
        unsigned short* Wt1 = (unsigned short*)(ws + h1_bytes + hm_bytes);
        unsigned short* Wt2 = Wt1 + 256 * 256;

        build_wt<<<256, 256, 0, stream>>>(Ws1, Wn1, Wt1, 128);
        build_wt<<<512, 256, 0, stream>>>(Ws2, Wn2, Wt2, 256);

        hipFuncSetAttribute((const void*)sage_v8_l1,
                            hipFuncAttributeMaxDynamicSharedMemorySize, 131072);
        hipFuncSetAttribute((const void*)sage_v8_l2,
                            hipFuncAttributeMaxDynamicSharedMemorySize, 131072);

        // layer 1: xm = [bf16(x) | mean4(x)]; DMA-pipelined GEMM, A read once
        mean_xb<<<M / 16, 256, 0, stream>>>(x, nbr, xm);
        sage_v8_l1<<<M / 256, 512, 131072, stream>>>(xm, Wt1, b1, h1);
        // layer 2: hm2 overwrites xm; DMA-pipelined GEMM, col-pairs adjacent
        mean_pass<256, unsigned short><<<M * 32 / 256, 256, 0, stream>>>(h1, nbr, xm);
        sage_v8_l2<<<(M / 256) * 2, 512, 131072, stream>>>(h1, xm, Wt2, b2, out);
    } else {
        unsigned short* h1 = (unsigned short*)ws;
        unsigned short* Wt1 = (unsigned short*)(ws + h1_bytes);
        unsigned short* Wt2 = Wt1 + 256 * 256;

        build_wt<<<256, 256, 0, stream>>>(Ws1, Wn1, Wt1, 128);
        build_wt<<<512, 256, 0, stream>>>(Ws2, Wn2, Wt2, 256);

        hipFuncSetAttribute((const void*)sage_v3<128, float, unsigned short>,
                            hipFuncAttributeMaxDynamicSharedMemorySize, 131072);
        hipFuncSetAttribute((const void*)sage_v3<256, unsigned short, float>,
                            hipFuncAttributeMaxDynamicSharedMemorySize, 131072);

        sage_v3<128, float, unsigned short>
            <<<dim3(M / 256, 1), 512, 131072, stream>>>(x, nbr, Wt1, b1, h1);
        sage_v3<256, unsigned short, float>
            <<<dim3(M / 512, 2), 512, 131072, stream>>>(h1, nbr, Wt2, b2, out);
    }
}